// Round 4
// baseline (479.985 us; speedup 1.0000x reference)
//
#include <hip/hip_runtime.h>
#include <hip/hip_bf16.h>

constexpr int kN = 8192;
constexpr int kD = 128;
constexpr int kV = 3;
constexpr int kNV = kV * kN;
constexpr int kMChunks = 8;               // m chunks (grid.y)
constexpr int kMc = kN / kMChunks;        // 1024 m per block
constexpr int kIters = kMc / 16;          // 64 m-tiles of 16
constexpr int kNBlk = 128;                // n per block = 4 waves x 32

typedef __attribute__((ext_vector_type(8))) short bf16x8;
typedef __attribute__((ext_vector_type(4))) float floatx4;

__device__ __forceinline__ unsigned pack_bf16(float a, float b) {
    unsigned ua = __float_as_uint(a);
    unsigned ub = __float_as_uint(b);
    ua = (ua + 0x7FFFu + ((ua >> 16) & 1u)) >> 16;   // RNE round to bf16
    ub = (ub + 0x7FFFu + ((ub >> 16) & 1u)) >> 16;
    return ua | (ub << 16);
}

// lgkmcnt(0) only; vmcnt/expcnt left at max so global loads stay in flight.
__device__ __forceinline__ void block_sync_lds() {
    __builtin_amdgcn_s_waitcnt(0xC07F);
    __builtin_amdgcn_s_barrier();
}

// One wave per row. Rows [0,kN): Hc (scale 1/T = 2.0 folded). Rows [kN,...): Hv flat.
__global__ void k_normalize(const float* __restrict__ Hc, const float* __restrict__ Hv,
                            unsigned* __restrict__ HcB, unsigned* __restrict__ HvB) {
    int row  = (blockIdx.x * blockDim.x + threadIdx.x) >> 6;
    int lane = threadIdx.x & 63;
    const float* src;
    unsigned* dst;
    float extra;
    if (row < kN) { src = Hc + (size_t)row * kD; dst = HcB + (size_t)row * (kD / 2); extra = 2.0f; }
    else {
        int r = row - kN;
        src = Hv + (size_t)r * kD; dst = HvB + (size_t)r * (kD / 2); extra = 1.0f;
    }
    float2 x = ((const float2*)src)[lane];
    float ss = x.x * x.x + x.y * x.y;
    ss += __shfl_xor(ss, 1);  ss += __shfl_xor(ss, 2);  ss += __shfl_xor(ss, 4);
    ss += __shfl_xor(ss, 8);  ss += __shfl_xor(ss, 16); ss += __shfl_xor(ss, 32);
    float inv = extra * rsqrtf(fmaxf(ss, 1e-24f));
    dst[lane] = pack_bf16(x.x * inv, x.y * inv);
}

// One wave per (v,n). Raw dot sums scattered into 256 partial slots.
__global__ void k_positive(const unsigned* __restrict__ HcB, const unsigned* __restrict__ HvB,
                           float* __restrict__ pos_partial) {
    int row  = (blockIdx.x * blockDim.x + threadIdx.x) >> 6;  // v*kN + n
    int lane = threadIdx.x & 63;
    int w    = threadIdx.x >> 6;
    int n    = row & (kN - 1);
    unsigned a = HcB[(size_t)n * (kD / 2) + lane];
    unsigned b = HvB[(size_t)row * (kD / 2) + lane];
    float dot = __uint_as_float(a << 16) * __uint_as_float(b << 16)
              + __uint_as_float(a & 0xFFFF0000u) * __uint_as_float(b & 0xFFFF0000u);
    dot += __shfl_xor(dot, 1);  dot += __shfl_xor(dot, 2);  dot += __shfl_xor(dot, 4);
    dot += __shfl_xor(dot, 8);  dot += __shfl_xor(dot, 16); dot += __shfl_xor(dot, 32);
    __shared__ float acc4[4];
    if (lane == 0) acc4[w] = dot;
    __syncthreads();
    if (threadIdx.x == 0)
        atomicAdd(&pos_partial[blockIdx.x & 255], acc4[0] + acc4[1] + acc4[2] + acc4[3]);
}

// n-slab / m-streaming. Wave owns 32 n (Hc B-frags + denom accumulators persistent
// in registers). S: per-lane float4, contiguous in m, register-pipelined depth 2,
// NEVER drained (raw lgkm-only barrier). Hv: LDS double buffer (L2-resident source).
__launch_bounds__(256, 2)
__global__ void k_main(const unsigned* __restrict__ HcB, const unsigned* __restrict__ HvB,
                       const float* __restrict__ S, float* __restrict__ denom) {
    __shared__ short HvT[2][kV][16 * 136];   // 136-short row stride: measured conflict-free

    const int tid  = threadIdx.x;
    const int w    = tid >> 6;
    const int lane = tid & 63;
    const int col  = lane & 15;
    const int quad = lane >> 4;
    const int n0w  = blockIdx.x * kNBlk + w * 32;
    const int mBase = blockIdx.y * kMc;

    const short* hc = (const short*)HcB;
    const short* hv = (const short*)HvB;

    // persistent B fragments (Hc, n role): B[k=quad*8+j][n=col]
    bf16x8 bfrag[2][4];
#pragma unroll
    for (int ns = 0; ns < 2; ++ns)
#pragma unroll
        for (int kk = 0; kk < 4; ++kk)
            bfrag[ns][kk] = *(const bf16x8*)(hc + (size_t)(n0w + ns * 16 + col) * kD + kk * 32 + quad * 8);

    // Hv staging map: thread -> (m-row, 16B chunk); one pass per view
    const int smRow = tid >> 4;
    const int smOff = tid & 15;

    // S row pointers for this lane's two n rows; quad*4 = m sub-offset
    const float* sRow0 = S + (size_t)(n0w + col) * kN + mBase + quad * 4;
    const float* sRow1 = S + (size_t)(n0w + 16 + col) * kN + mBase + quad * 4;

    // depth-2 S register pipeline
    float4 sBuf[2][2];
    sBuf[0][0] = *(const float4*)(sRow0);
    sBuf[0][1] = *(const float4*)(sRow1);
    sBuf[1][0] = *(const float4*)(sRow0 + 16);
    sBuf[1][1] = *(const float4*)(sRow1 + 16);

    // stage Hv tile 0
    {
        const size_t srcBase = (size_t)(mBase + smRow) * kD + smOff * 8;
#pragma unroll
        for (int v = 0; v < kV; ++v) {
            float4 t = *(const float4*)(hv + (size_t)v * kN * kD + srcBase);
            *(float4*)&HvT[0][v][smRow * 136 + smOff * 8] = t;
        }
    }
    block_sync_lds();

    float dv[kV][2] = {{0.f, 0.f}, {0.f, 0.f}, {0.f, 0.f}};

    for (int it = 0; it < kIters; ++it) {
        const int cur = it & 1, nxt = cur ^ 1;

        // issue Hv prefetch for tile it+1 (clamped re-read on last iter; discarded)
        const int itH = (it + 1 < kIters) ? it + 1 : it;
        float4 hvReg[kV];
        {
            const size_t srcBase = (size_t)(mBase + itH * 16 + smRow) * kD + smOff * 8;
#pragma unroll
            for (int v = 0; v < kV; ++v)
                hvReg[v] = *(const float4*)(hv + (size_t)v * kN * kD + srcBase);
        }

        // consume S (loaded 2 iters ago), then refill the slot for it+2
        const float4 s0 = sBuf[cur][0], s1 = sBuf[cur][1];
        const float w00 = 1.f - s0.x, w01 = 1.f - s0.y, w02 = 1.f - s0.z, w03 = 1.f - s0.w;
        const float w10 = 1.f - s1.x, w11 = 1.f - s1.y, w12 = 1.f - s1.z, w13 = 1.f - s1.w;
        const int itS = (it + 2 < kIters) ? it + 2 : it;
        sBuf[cur][0] = *(const float4*)(sRow0 + itS * 16);
        sBuf[cur][1] = *(const float4*)(sRow1 + itS * 16);

#pragma unroll
        for (int v = 0; v < kV; ++v) {
            bf16x8 a[4];
#pragma unroll
            for (int kk = 0; kk < 4; ++kk)
                a[kk] = *(const bf16x8*)&HvT[cur][v][col * 136 + kk * 32 + quad * 8];
            floatx4 acc0 = {0.f, 0.f, 0.f, 0.f}, acc1 = {0.f, 0.f, 0.f, 0.f};
#pragma unroll
            for (int kk = 0; kk < 4; ++kk) {
                acc0 = __builtin_amdgcn_mfma_f32_16x16x32_bf16(a[kk], bfrag[0][kk], acc0, 0, 0, 0);
                acc1 = __builtin_amdgcn_mfma_f32_16x16x32_bf16(a[kk], bfrag[1][kk], acc1, 0, 0, 0);
            }
            dv[v][0] += w00 * __expf(acc0[0]) + w01 * __expf(acc0[1])
                      + w02 * __expf(acc0[2]) + w03 * __expf(acc0[3]);
            dv[v][1] += w10 * __expf(acc1[0]) + w11 * __expf(acc1[1])
                      + w12 * __expf(acc1[2]) + w13 * __expf(acc1[3]);
        }

        // commit staged Hv into the other buffer (prev iter's readers passed the barrier)
#pragma unroll
        for (int v = 0; v < kV; ++v)
            *(float4*)&HvT[nxt][v][smRow * 136 + smOff * 8] = hvReg[v];
        block_sync_lds();
    }

    // register denom partials -> reduce over quad -> one atomic per (v, n)
#pragma unroll
    for (int v = 0; v < kV; ++v)
#pragma unroll
        for (int ns = 0; ns < 2; ++ns) {
            float p = dv[v][ns];
            p += __shfl_xor(p, 16);
            p += __shfl_xor(p, 32);
            if (quad == 0)
                atomicAdd(&denom[(size_t)v * kN + n0w + ns * 16 + col], p);
        }
}

__global__ void k_final(const float* __restrict__ denom, const float* __restrict__ pos_partial,
                        float* __restrict__ out) {
    int idx  = blockIdx.x * 256 + threadIdx.x;   // 0..kNV-1
    int lane = threadIdx.x & 63;
    int w    = threadIdx.x >> 6;
    float val = logf(fmaxf(denom[idx], 1e-9f));
    if (blockIdx.x == 0) val -= pos_partial[threadIdx.x];   // fold positive term once
    val += __shfl_xor(val, 1);  val += __shfl_xor(val, 2);  val += __shfl_xor(val, 4);
    val += __shfl_xor(val, 8);  val += __shfl_xor(val, 16); val += __shfl_xor(val, 32);
    __shared__ float acc4[4];
    if (lane == 0) acc4[w] = val;
    __syncthreads();
    if (threadIdx.x == 0)
        atomicAdd(out, (acc4[0] + acc4[1] + acc4[2] + acc4[3]) * (1.0f / kNV));
}

extern "C" void kernel_launch(void* const* d_in, const int* in_sizes, int n_in,
                              void* d_out, int out_size, void* d_ws, size_t ws_size,
                              hipStream_t stream) {
    const float* Hc = (const float*)d_in[0];   // [N, D] fp32
    const float* S  = (const float*)d_in[1];   // [N, N] fp32
    const float* Hv = (const float*)d_in[2];   // [V, N, D] fp32

    unsigned* HcB  = (unsigned*)d_ws;                            // 2 MB
    unsigned* HvB  = HcB + (size_t)kN * (kD / 2);                // 6 MB
    float*    den  = (float*)(HvB + (size_t)kV * kN * (kD / 2)); // kNV floats
    float*    posp = den + kNV;                                  // 256 floats
    float*    outF = (float*)d_out;

    hipMemsetAsync(den, 0, ((size_t)kNV + 256) * sizeof(float), stream);
    hipMemsetAsync(outF, 0, sizeof(float), stream);

    k_normalize<<<dim3((kN + kV * kN) / 4), 256, 0, stream>>>(Hc, Hv, HcB, HvB);
    k_positive<<<dim3(kNV / 4), 256, 0, stream>>>(HcB, HvB, posp);
    k_main<<<dim3(kN / kNBlk, kMChunks), dim3(256), 0, stream>>>(HcB, HvB, S, den);
    k_final<<<dim3(kNV / 256), dim3(256), 0, stream>>>(den, posp, outF);
}